// Round 3
// baseline (12949.422 us; speedup 1.0000x reference)
//
#include <hip/hip_runtime.h>
#include <cstdint>
#include <cstddef>

// Problem constants (B,T,D,H,L = 16,4096,256,256,2)
#define T_SEQ 4096
#define BATCH 16
#define HID   256
#define GATES 1024   // 4*H, torch gate order i,f,g,o
#define DIN   256

typedef _Float16 h2 __attribute__((ext_vector_type(2)));
typedef _Float16 h8 __attribute__((ext_vector_type(8)));
typedef float    f4 __attribute__((ext_vector_type(4)));

// ---- K2 geometry -----------------------------------------------------------
// 512 threads/WG, one WG per batch. Thread (kq=tid&3, u2=tid>>2) owns the
// 8 gate rows {i,f,g,o} x {j0=2*u2, j1=j0+1} restricted to K in [64*kq,64*kq+64).
// Per-row 32 h2 weights split by h8-chunk: chunks 0..5 -> VGPR (192 h2),
// chunk 6 -> LDS [r][tid] (64KB resident, conflict-free stride-16 reads),
// chunk 7 -> L2-packed global wres [r][tid] (coalesced dwordx4).
#define LDSW6_BYTES (512 * 128)            // 65536
#define K2HBUF      (2 * HID * 2)          // 1024  (double-buffered f16 h)
#define K2PBUF      (2 * 8 * 4)            // 64    (per-wave logit partials)
#define K2_LDS      (LDSW6_BYTES + K2HBUF + K2PBUF)   // 66624

__device__ __forceinline__ float dot2f(h2 a, h2 b, float c) {
#if __has_builtin(__builtin_amdgcn_fdot2)
  return __builtin_amdgcn_fdot2(a, b, c, false);
#else
  return c + (float)a[0] * (float)b[0] + (float)a[1] * (float)b[1];
#endif
}

template <int I>
__device__ __forceinline__ h2 get2(h8 v) { return (h2){v[2 * I], v[2 * I + 1]}; }

// DPP add: x + dpp_perm(x).  CTRL: 0xB1=xor1, 0x4E=xor2, 0x124=ror:4,
// 0x128=ror:8, 0x12C=ror:12, 0x142=row_bcast15, 0x143=row_bcast31.
template <int CTRL>
__device__ __forceinline__ float dppadd(float x) {
  int v = __builtin_amdgcn_mov_dpp(__float_as_int(x), CTRL, 0xF, 0xF, true);
  return x + __int_as_float(v);
}

__device__ __forceinline__ float xhalf(unsigned u, int hi) {
  h2 p; __builtin_memcpy(&p, &u, 4);
  return hi ? (float)p[1] : (float)p[0];
}

__device__ __forceinline__ float sigmf_(float x) {
  x = fminf(fmaxf(x, -30.0f), 30.0f);
  return 1.0f / (1.0f + __expf(-x));
}
__device__ __forceinline__ float tanhf_(float x) {
  x = fminf(fmaxf(x, -15.0f), 15.0f);
  const float e = __expf(2.0f * x);
  return (e - 1.0f) / (e + 1.0f);
}

__device__ __forceinline__ h8 cvt8(float4 a, float4 b) {
  return (h8){(_Float16)a.x, (_Float16)a.y, (_Float16)a.z, (_Float16)a.w,
              (_Float16)b.x, (_Float16)b.y, (_Float16)b.z, (_Float16)b.w};
}

// ---------------------------------------------------------------------------
// K0: pack chunk-7 weight slices (h indices [kk+56,kk+64)) as f16 in the
// exact per-thread layout K2 streams each step: wres[r*512+tid] = h8.
// ---------------------------------------------------------------------------
__global__ __launch_bounds__(512) void k0_pack(const float* __restrict__ Whh,
                                               _Float16* __restrict__ wres) {
  const int tid = threadIdx.x;
  const int kq = tid & 3, u2 = tid >> 2;
  const int j0 = 2 * u2, kk = kq * 64;
  #pragma unroll
  for (int r = 0; r < 8; ++r) {
    const int row = (r & 3) * 256 + j0 + (r >> 2);
    const float* wp = Whh + (size_t)row * HID + kk + 56;
    const float4 f0 = *(const float4*)wp;
    const float4 f1 = *(const float4*)(wp + 4);
    *(h8*)(wres + ((size_t)r * 512 + tid) * 8) = cvt8(f0, f1);
  }
}

// ---------------------------------------------------------------------------
// K1: xp[m][g] = sum_k x[m][k]*Wih[g][k] + bih[g] + bhh[g], stored f16.
// 256x64 supertile per 256-thread WG: B-fragments hoisted across 4 M-subtiles
// (B traffic and cvt cost / 4 vs round-1).  MFMA f32_16x16x32_f16.
// ---------------------------------------------------------------------------
__global__ __launch_bounds__(256) void k1_xproj(
    const float* __restrict__ x, const float* __restrict__ Wih,
    const float* __restrict__ bih, const float* __restrict__ bhh,
    _Float16* __restrict__ xp) {
  const int bid = blockIdx.x;
  const int ms = bid >> 4;          // 256 M-supertiles of 256 rows
  const int nt = bid & 15;          // 16 N-tiles of 64 cols
  const int tid = threadIdx.x;
  const int wv = tid >> 6;
  const int l  = tid & 63;
  const int lr = l & 15;
  const int lq = l >> 4;

  f4 acc[4][4] = {};
  for (int ks = 0; ks < 8; ++ks) {
    const int k0 = ks * 32 + lq * 8;
    h8 bf[4];
    #pragma unroll
    for (int n = 0; n < 4; ++n) {
      const int col = nt * 64 + n * 16 + lr;
      const float* wr = Wih + (size_t)col * DIN + k0;
      bf[n] = cvt8(*(const float4*)wr, *(const float4*)(wr + 4));
    }
    #pragma unroll
    for (int m = 0; m < 4; ++m) {
      const int arow = ms * 256 + m * 64 + wv * 16 + lr;
      const float* xr = x + (size_t)arow * DIN + k0;
      const h8 af = cvt8(*(const float4*)xr, *(const float4*)(xr + 4));
      #pragma unroll
      for (int n = 0; n < 4; ++n)
        acc[m][n] = __builtin_amdgcn_mfma_f32_16x16x32_f16(af, bf[n], acc[m][n], 0, 0, 0);
    }
  }
  #pragma unroll
  for (int n = 0; n < 4; ++n) {
    const int col = nt * 64 + n * 16 + lr;
    const float bias = bih[col] + bhh[col];
    #pragma unroll
    for (int m = 0; m < 4; ++m) {
      #pragma unroll
      for (int rI = 0; rI < 4; ++rI) {
        const int row = ms * 256 + m * 64 + wv * 16 + lq * 4 + rI;
        xp[(size_t)row * GATES + col] = (_Float16)(acc[m][n][rI] + bias);
      }
    }
  }
}

// ---------------------------------------------------------------------------
// K2: sequential LSTM, one WG per batch.  R=8/S=4 decomposition, DPP quad
// reduction, single barrier per step, fused epilogue part A:
//   out = 2h - w*fw + inc*(fw-bw);  tot saved for K3.
// ---------------------------------------------------------------------------
__global__ __launch_bounds__(512, 2) void k2_lstm(
    const _Float16* __restrict__ xp, const float* __restrict__ Whh,
    const _Float16* __restrict__ wres,
    const float* __restrict__ Wlin, const float* __restrict__ blin,
    const float* __restrict__ fw, const float* __restrict__ bw,
    float* __restrict__ out, float* __restrict__ tot) {
  extern __shared__ __align__(16) char smem[];
  _Float16* w6   = (_Float16*)smem;                         // [8][512][8] f16
  _Float16* hbuf = (_Float16*)(smem + LDSW6_BYTES);         // [2][256] f16
  float*    pbuf = (float*)(smem + LDSW6_BYTES + K2HBUF);   // [2][8] f32

  const int b    = blockIdx.x;
  const int tid  = threadIdx.x;
  const int lane = tid & 63;
  const int kq   = tid & 3;
  const int u2   = tid >> 2;
  const int j0   = 2 * u2;
  const int kk   = kq * 64;

  if (tid < 128) ((float*)hbuf)[tid] = 0.0f;   // zero h-buffer 0

  // Register-resident weights: chunks 0..5 of each of the 8 rows.
  h8 wreg[8][6];
  #pragma unroll
  for (int r = 0; r < 8; ++r) {
    const int row = (r & 3) * 256 + j0 + (r >> 2);
    const float* wp = Whh + (size_t)row * HID + kk;
    #pragma unroll
    for (int c = 0; c < 6; ++c)
      wreg[r][c] = cvt8(*(const float4*)(wp + c * 8), *(const float4*)(wp + c * 8 + 4));
    // chunk 6 -> LDS, layout [r][tid]
    *(h8*)(w6 + ((size_t)r * 512 + tid) * 8) =
        cvt8(*(const float4*)(wp + 48), *(const float4*)(wp + 52));
  }

  const float fw0 = fw[j0], fw1 = fw[j0 + 1];
  const float dfw0 = fw0 - bw[j0], dfw1 = fw1 - bw[j0 + 1];
  const float dw0 = Wlin[HID + j0] - Wlin[j0];
  const float dw1 = Wlin[HID + j0 + 1] - Wlin[j0 + 1];
  const float db  = blin[1] - blin[0];

  float c0 = 0.f, c1 = 0.f, inc0 = 0.f, inc1 = 0.f;

  const unsigned* xpu = (const unsigned*)(xp + (size_t)b * T_SEQ * GATES);
  const int xoff = kq * 128 + u2;           // dword index within a step
  float* outb = out + (size_t)b * T_SEQ * HID;
  const h8* wres8 = (const h8*)wres;

  unsigned xq0 = xpu[xoff];
  unsigned xq1 = xpu[512 + xoff];

  __syncthreads();

  #pragma unroll 1
  for (int t = 0; t < T_SEQ; ++t) {
    const int rb = t & 1, wb = rb ^ 1;

    int tp = t + 2; if (tp > T_SEQ - 1) tp = T_SEQ - 1;
    const unsigned xq2 = xpu[(size_t)tp * 512 + xoff];

    // issue chunk-7 weight stream (L2-resident, coalesced)
    h8 w7[8];
    #pragma unroll
    for (int r = 0; r < 8; ++r) w7[r] = wres8[r * 512 + tid];

    float acc[8] = {0.f, 0.f, 0.f, 0.f, 0.f, 0.f, 0.f, 0.f};
    const _Float16* hb = hbuf + rb * HID + kk;

    #pragma unroll
    for (int c = 0; c < 6; ++c) {
      const h8 hv = *(const h8*)(hb + c * 8);
      #pragma unroll
      for (int r = 0; r < 8; ++r) {
        acc[r] = dot2f(get2<0>(wreg[r][c]), get2<0>(hv), acc[r]);
        acc[r] = dot2f(get2<1>(wreg[r][c]), get2<1>(hv), acc[r]);
        acc[r] = dot2f(get2<2>(wreg[r][c]), get2<2>(hv), acc[r]);
        acc[r] = dot2f(get2<3>(wreg[r][c]), get2<3>(hv), acc[r]);
      }
    }
    {  // chunk 6 from LDS
      const h8 hv = *(const h8*)(hb + 48);
      #pragma unroll
      for (int r = 0; r < 8; ++r) {
        const h8 wv = *(const h8*)(w6 + ((size_t)r * 512 + tid) * 8);
        acc[r] = dot2f(get2<0>(wv), get2<0>(hv), acc[r]);
        acc[r] = dot2f(get2<1>(wv), get2<1>(hv), acc[r]);
        acc[r] = dot2f(get2<2>(wv), get2<2>(hv), acc[r]);
        acc[r] = dot2f(get2<3>(wv), get2<3>(hv), acc[r]);
      }
    }
    {  // chunk 7 from global (already in w7)
      const h8 hv = *(const h8*)(hb + 56);
      #pragma unroll
      for (int r = 0; r < 8; ++r) {
        acc[r] = dot2f(get2<0>(w7[r]), get2<0>(hv), acc[r]);
        acc[r] = dot2f(get2<1>(w7[r]), get2<1>(hv), acc[r]);
        acc[r] = dot2f(get2<2>(w7[r]), get2<2>(hv), acc[r]);
        acc[r] = dot2f(get2<3>(w7[r]), get2<3>(hv), acc[r]);
      }
    }

    // broadcast xp gate-pairs across the quad (lane kq holds gate kq)
    const int xi = (int)xq0;
    const unsigned xg0 = (unsigned)__builtin_amdgcn_mov_dpp(xi, 0x00, 0xF, 0xF, true);
    const unsigned xg1 = (unsigned)__builtin_amdgcn_mov_dpp(xi, 0x55, 0xF, 0xF, true);
    const unsigned xg2 = (unsigned)__builtin_amdgcn_mov_dpp(xi, 0xAA, 0xF, 0xF, true);
    const unsigned xg3 = (unsigned)__builtin_amdgcn_mov_dpp(xi, 0xFF, 0xF, 0xF, true);

    // quad reduction (commutative adds -> bitwise identical in all 4 lanes)
    float pre[8];
    #pragma unroll
    for (int r = 0; r < 8; ++r) {
      float s = acc[r];
      s = dppadd<0xB1>(s);
      s = dppadd<0x4E>(s);
      pre[r] = s;
    }
    pre[0] += xhalf(xg0, 0); pre[4] += xhalf(xg0, 1);
    pre[1] += xhalf(xg1, 0); pre[5] += xhalf(xg1, 1);
    pre[2] += xhalf(xg2, 0); pre[6] += xhalf(xg2, 1);
    pre[3] += xhalf(xg3, 0); pre[7] += xhalf(xg3, 1);

    // activations (i,f,g,o) for units j0, j0+1 (all 4 lanes, identical)
    c0 = sigmf_(pre[1]) * c0 + sigmf_(pre[0]) * tanhf_(pre[2]);
    const float h0 = sigmf_(pre[3]) * tanhf_(c0);
    c1 = sigmf_(pre[5]) * c1 + sigmf_(pre[4]) * tanhf_(pre[6]);
    const float h1 = sigmf_(pre[7]) * tanhf_(c1);

    if (kq == 0) {
      h2 hh = {(_Float16)h0, (_Float16)h1};
      *(h2*)(hbuf + wb * HID + j0) = hh;
    }

    // logit-diff wave partial (nonzero only on kq==0 lanes)
    float p = (kq == 0) ? (h0 * dw0 + h1 * dw1) : 0.0f;
    p = dppadd<0xB1>(p);   // quad
    p = dppadd<0x4E>(p);
    p = dppadd<0x124>(p);  // row-of-16
    p = dppadd<0x128>(p);
    p = dppadd<0x142>(p);  // rows -> lane 63
    p = dppadd<0x143>(p);
    if (lane == 63) pbuf[rb * 8 + (tid >> 6)] = p;

    __syncthreads();   // h_t and wave partials visible

    float pv = pbuf[rb * 8 + (lane & 7)];
    pv = dppadd<0xB1>(pv);
    pv = dppadd<0x4E>(pv);
    pv = dppadd<0x12C>(pv);
    const float d = pv + db;
    const float gf = (d > 0.0f) ? 1.0f : 0.0f;   // argmax (ties -> class 0)

    if (kq == 0) {
      const float wv0 = gf * h0, wv1 = gf * h1;
      inc0 += wv0; inc1 += wv1;
      float2 ov;
      ov.x = 2.0f * h0 - wv0 * fw0 + inc0 * dfw0;
      ov.y = 2.0f * h1 - wv1 * fw1 + inc1 * dfw1;
      *(float2*)(outb + (size_t)t * HID + j0) = ov;
    }

    xq0 = xq1; xq1 = xq2;
  }

  if (kq == 0) {
    float2 tv; tv.x = inc0; tv.y = inc1;
    *(float2*)(tot + b * HID + j0) = tv;
  }
}

// ---------------------------------------------------------------------------
// K3: out += tot[b,j] * bw[j]   (suffix total term), vectorized float4
// ---------------------------------------------------------------------------
__global__ __launch_bounds__(256) void k3_add(
    float* __restrict__ out, const float* __restrict__ tot,
    const float* __restrict__ bw) {
  const int gid = blockIdx.x * 256 + threadIdx.x;
  const size_t e = (size_t)gid * 4;
  const int b  = (int)(e >> 20);             // 4096*256 = 2^20 elems per batch
  const int jb = ((int)(e & 255)) >> 2;
  float4 v = ((float4*)out)[gid];
  const float4 tt = ((const float4*)tot)[b * 64 + jb];
  const float4 bb = ((const float4*)bw)[jb];
  v.x += tt.x * bb.x; v.y += tt.y * bb.y;
  v.z += tt.z * bb.z; v.w += tt.w * bb.w;
  ((float4*)out)[gid] = v;
}

extern "C" void kernel_launch(void* const* d_in, const int* in_sizes, int n_in,
                              void* d_out, int out_size, void* d_ws, size_t ws_size,
                              hipStream_t stream) {
  const float* x    = (const float*)d_in[0];
  const float* Wih  = (const float*)d_in[1];
  const float* Whh  = (const float*)d_in[2];
  const float* bih  = (const float*)d_in[3];
  const float* bhh  = (const float*)d_in[4];
  const float* Wlin = (const float*)d_in[5];
  const float* blin = (const float*)d_in[6];
  const float* fw   = (const float*)d_in[7];
  const float* bw   = (const float*)d_in[8];
  float* out = (float*)d_out;

  // Workspace: xp f16 [65536][1024] = 128 MiB, tot f32 [16][256], wres 64 KiB
  _Float16* xpw  = (_Float16*)d_ws;
  float*    tot  = (float*)((char*)d_ws + (size_t)BATCH * T_SEQ * GATES * 2);
  _Float16* wres = (_Float16*)((char*)d_ws + (size_t)BATCH * T_SEQ * GATES * 2 + 16384);

  k0_pack<<<dim3(1), dim3(512), 0, stream>>>(Whh, wres);

  k1_xproj<<<dim3(4096), dim3(256), 0, stream>>>(x, Wih, bih, bhh, xpw);

  (void)hipFuncSetAttribute((const void*)k2_lstm,
                            hipFuncAttributeMaxDynamicSharedMemorySize, K2_LDS);
  k2_lstm<<<dim3(BATCH), dim3(512), K2_LDS, stream>>>(xpw, Whh, wres, Wlin, blin,
                                                      fw, bw, out, tot);

  k3_add<<<dim3(16384), dim3(256), 0, stream>>>(out, tot, bw);
}

// Round 4
// 9364.739 us; speedup vs baseline: 1.3828x; 1.3828x over previous
//
#include <hip/hip_runtime.h>
#include <cstdint>
#include <cstddef>

// Problem constants (B,T,D,H,L = 16,4096,256,256,2)
#define T_SEQ 4096
#define BATCH 16
#define HID   256
#define GATES 1024   // 4*H, torch gate order i,f,g,o
#define DIN   256

typedef _Float16 h2 __attribute__((ext_vector_type(2)));
typedef _Float16 h8 __attribute__((ext_vector_type(8)));
typedef float    f4 __attribute__((ext_vector_type(4)));

// ---- K2 geometry -----------------------------------------------------------
// 512 threads/WG, one WG per batch. Thread (kq=tid&3, u2=tid>>2) owns the
// 8 gate rows {i,f,g,o} x {j0=2*u2, j1=j0+1} restricted to K in [64*kq,64*kq+64).
// Per-row 32 h2 weights split by h8-chunk:
//   chunks 0..4 -> VGPR (160 VGPRs persistent; launch_bounds(512,1) = 256 cap)
//   chunks 5,6  -> LDS [r][tid] (2 x 64KB resident, conflict-free b128)
//   chunk  7    -> L2-packed global wres [r][tid], streamed each step
// h double-buffer padded: [2][4][72] f16 -> quarter bases on banks {0,4,8,12}.
#define HQ 72
#define LDSW_BYTES  (2 * 512 * 128)                 // 131072 (w5 + w6)
#define K2HBUF      (2 * 4 * HQ * 2)                // 1152
#define K2PBUF      (2 * 8 * 4)                     // 64
#define K2_LDS      (LDSW_BYTES + K2HBUF + K2PBUF)  // 132288

__device__ __forceinline__ float dot2f(h2 a, h2 b, float c) {
#if __has_builtin(__builtin_amdgcn_fdot2)
  return __builtin_amdgcn_fdot2(a, b, c, false);
#else
  return c + (float)a[0] * (float)b[0] + (float)a[1] * (float)b[1];
#endif
}

template <int I>
__device__ __forceinline__ h2 get2(h8 v) { return (h2){v[2 * I], v[2 * I + 1]}; }

// DPP add: x + dpp_perm(x).  CTRL: 0xB1=xor1, 0x4E=xor2, 0x124=ror:4,
// 0x128=ror:8, 0x12C=ror:12, 0x142=row_bcast15, 0x143=row_bcast31.
template <int CTRL>
__device__ __forceinline__ float dppadd(float x) {
  int v = __builtin_amdgcn_mov_dpp(__float_as_int(x), CTRL, 0xF, 0xF, true);
  return x + __int_as_float(v);
}

__device__ __forceinline__ float xhalf(unsigned u, int hi) {
  h2 p; __builtin_memcpy(&p, &u, 4);
  return hi ? (float)p[1] : (float)p[0];
}

__device__ __forceinline__ float sigmf_(float x) {
  x = fminf(fmaxf(x, -30.0f), 30.0f);
  return 1.0f / (1.0f + __expf(-x));
}
__device__ __forceinline__ float tanhf_(float x) {
  x = fminf(fmaxf(x, -15.0f), 15.0f);
  const float e = __expf(2.0f * x);
  return (e - 1.0f) / (e + 1.0f);
}

__device__ __forceinline__ h8 cvt8(float4 a, float4 b) {
  return (h8){(_Float16)a.x, (_Float16)a.y, (_Float16)a.z, (_Float16)a.w,
              (_Float16)b.x, (_Float16)b.y, (_Float16)b.z, (_Float16)b.w};
}

// ---------------------------------------------------------------------------
// K0: pack chunk-7 weight slices (h indices [kk+56,kk+64)) as f16 in the
// exact per-thread layout K2 streams each step: wres[r*512+tid] = h8.
// ---------------------------------------------------------------------------
__global__ __launch_bounds__(512) void k0_pack(const float* __restrict__ Whh,
                                               _Float16* __restrict__ wres) {
  const int tid = threadIdx.x;
  const int kq = tid & 3, u2 = tid >> 2;
  const int j0 = 2 * u2, kk = kq * 64;
  #pragma unroll
  for (int r = 0; r < 8; ++r) {
    const int row = (r & 3) * 256 + j0 + (r >> 2);
    const float* wp = Whh + (size_t)row * HID + kk + 56;
    const float4 f0 = *(const float4*)wp;
    const float4 f1 = *(const float4*)(wp + 4);
    *(h8*)(wres + ((size_t)r * 512 + tid) * 8) = cvt8(f0, f1);
  }
}

// ---------------------------------------------------------------------------
// K1: xp[m][g] = sum_k x[m][k]*Wih[g][k] + bih[g] + bhh[g], stored f16.
// 256x64 supertile per 256-thread WG.  MFMA f32_16x16x32_f16.
// ---------------------------------------------------------------------------
__global__ __launch_bounds__(256) void k1_xproj(
    const float* __restrict__ x, const float* __restrict__ Wih,
    const float* __restrict__ bih, const float* __restrict__ bhh,
    _Float16* __restrict__ xp) {
  const int bid = blockIdx.x;
  const int ms = bid >> 4;          // 256 M-supertiles of 256 rows
  const int nt = bid & 15;          // 16 N-tiles of 64 cols
  const int tid = threadIdx.x;
  const int wv = tid >> 6;
  const int l  = tid & 63;
  const int lr = l & 15;
  const int lq = l >> 4;

  f4 acc[4][4] = {};
  for (int ks = 0; ks < 8; ++ks) {
    const int k0 = ks * 32 + lq * 8;
    h8 bf[4];
    #pragma unroll
    for (int n = 0; n < 4; ++n) {
      const int col = nt * 64 + n * 16 + lr;
      const float* wr = Wih + (size_t)col * DIN + k0;
      bf[n] = cvt8(*(const float4*)wr, *(const float4*)(wr + 4));
    }
    #pragma unroll
    for (int m = 0; m < 4; ++m) {
      const int arow = ms * 256 + m * 64 + wv * 16 + lr;
      const float* xr = x + (size_t)arow * DIN + k0;
      const h8 af = cvt8(*(const float4*)xr, *(const float4*)(xr + 4));
      #pragma unroll
      for (int n = 0; n < 4; ++n)
        acc[m][n] = __builtin_amdgcn_mfma_f32_16x16x32_f16(af, bf[n], acc[m][n], 0, 0, 0);
    }
  }
  #pragma unroll
  for (int n = 0; n < 4; ++n) {
    const int col = nt * 64 + n * 16 + lr;
    const float bias = bih[col] + bhh[col];
    #pragma unroll
    for (int m = 0; m < 4; ++m) {
      #pragma unroll
      for (int rI = 0; rI < 4; ++rI) {
        const int row = ms * 256 + m * 64 + wv * 16 + lq * 4 + rI;
        xp[(size_t)row * GATES + col] = (_Float16)(acc[m][n][rI] + bias);
      }
    }
  }
}

// ---------------------------------------------------------------------------
// K2: sequential LSTM, one WG per batch.  R=8/S=4 decomposition, DPP quad
// reduction, single barrier per step, fused epilogue part A:
//   out = 2h - w*fw + inc*(fw-bw);  tot saved for K3.
// ---------------------------------------------------------------------------
__global__ __launch_bounds__(512, 1) void k2_lstm(
    const _Float16* __restrict__ xp, const float* __restrict__ Whh,
    const _Float16* __restrict__ wres,
    const float* __restrict__ Wlin, const float* __restrict__ blin,
    const float* __restrict__ fw, const float* __restrict__ bw,
    float* __restrict__ out, float* __restrict__ tot) {
  extern __shared__ __align__(16) char smem[];
  _Float16* w5   = (_Float16*)smem;                         // [8][512][8] f16
  _Float16* w6   = (_Float16*)(smem + 65536);               // [8][512][8] f16
  _Float16* hbuf = (_Float16*)(smem + LDSW_BYTES);          // [2][4][72] f16
  float*    pbuf = (float*)(smem + LDSW_BYTES + K2HBUF);    // [2][8] f32

  const int b    = blockIdx.x;
  const int tid  = threadIdx.x;
  const int lane = tid & 63;
  const int kq   = tid & 3;
  const int u2   = tid >> 2;
  const int j0   = 2 * u2;
  const int kk   = kq * 64;

  if (tid < 144) ((float*)hbuf)[tid] = 0.0f;   // zero h-buffer 0 (incl. pad)

  // Register-resident weights: chunks 0..4 of each of the 8 rows.
  h8 wreg[8][5];
  #pragma unroll
  for (int r = 0; r < 8; ++r) {
    const int row = (r & 3) * 256 + j0 + (r >> 2);
    const float* wp = Whh + (size_t)row * HID + kk;
    #pragma unroll
    for (int c = 0; c < 5; ++c)
      wreg[r][c] = cvt8(*(const float4*)(wp + c * 8), *(const float4*)(wp + c * 8 + 4));
    // chunks 5,6 -> LDS, layout [r][tid]
    *(h8*)(w5 + ((size_t)r * 512 + tid) * 8) =
        cvt8(*(const float4*)(wp + 40), *(const float4*)(wp + 44));
    *(h8*)(w6 + ((size_t)r * 512 + tid) * 8) =
        cvt8(*(const float4*)(wp + 48), *(const float4*)(wp + 52));
  }

  const float fw0 = fw[j0], fw1 = fw[j0 + 1];
  const float dfw0 = fw0 - bw[j0], dfw1 = fw1 - bw[j0 + 1];
  const float dw0 = Wlin[HID + j0] - Wlin[j0];
  const float dw1 = Wlin[HID + j0 + 1] - Wlin[j0 + 1];
  const float db  = blin[1] - blin[0];

  float c0 = 0.f, c1 = 0.f, inc0 = 0.f, inc1 = 0.f;

  const unsigned* xpu = (const unsigned*)(xp + (size_t)b * T_SEQ * GATES);
  const int xoff = kq * 128 + u2;           // dword index within a step
  float* outb = out + (size_t)b * T_SEQ * HID;
  const h8* wres8 = (const h8*)wres;

  unsigned xq0 = xpu[xoff];
  unsigned xq1 = xpu[512 + xoff];

  __syncthreads();

  #pragma unroll 1
  for (int t = 0; t < T_SEQ; ++t) {
    const int rb = t & 1, wb = rb ^ 1;

    int tp = t + 2; if (tp > T_SEQ - 1) tp = T_SEQ - 1;
    const unsigned xq2 = xpu[(size_t)tp * 512 + xoff];

    // issue chunk-7 weight stream early (L2-resident, coalesced)
    h8 w7[8];
    #pragma unroll
    for (int r = 0; r < 8; ++r) w7[r] = wres8[r * 512 + tid];

    float acc[8] = {0.f, 0.f, 0.f, 0.f, 0.f, 0.f, 0.f, 0.f};
    const _Float16* hb = hbuf + ((size_t)rb * 4 + kq) * HQ;

    #pragma unroll
    for (int c = 0; c < 5; ++c) {
      const h8 hv = *(const h8*)(hb + c * 8);
      #pragma unroll
      for (int r = 0; r < 8; ++r) {
        acc[r] = dot2f(get2<0>(wreg[r][c]), get2<0>(hv), acc[r]);
        acc[r] = dot2f(get2<1>(wreg[r][c]), get2<1>(hv), acc[r]);
        acc[r] = dot2f(get2<2>(wreg[r][c]), get2<2>(hv), acc[r]);
        acc[r] = dot2f(get2<3>(wreg[r][c]), get2<3>(hv), acc[r]);
      }
    }
    {  // chunk 5 from LDS
      const h8 hv = *(const h8*)(hb + 40);
      #pragma unroll
      for (int r = 0; r < 8; ++r) {
        const h8 wv = *(const h8*)(w5 + ((size_t)r * 512 + tid) * 8);
        acc[r] = dot2f(get2<0>(wv), get2<0>(hv), acc[r]);
        acc[r] = dot2f(get2<1>(wv), get2<1>(hv), acc[r]);
        acc[r] = dot2f(get2<2>(wv), get2<2>(hv), acc[r]);
        acc[r] = dot2f(get2<3>(wv), get2<3>(hv), acc[r]);
      }
    }
    {  // chunk 6 from LDS
      const h8 hv = *(const h8*)(hb + 48);
      #pragma unroll
      for (int r = 0; r < 8; ++r) {
        const h8 wv = *(const h8*)(w6 + ((size_t)r * 512 + tid) * 8);
        acc[r] = dot2f(get2<0>(wv), get2<0>(hv), acc[r]);
        acc[r] = dot2f(get2<1>(wv), get2<1>(hv), acc[r]);
        acc[r] = dot2f(get2<2>(wv), get2<2>(hv), acc[r]);
        acc[r] = dot2f(get2<3>(wv), get2<3>(hv), acc[r]);
      }
    }
    {  // chunk 7 from global (already in w7)
      const h8 hv = *(const h8*)(hb + 56);
      #pragma unroll
      for (int r = 0; r < 8; ++r) {
        acc[r] = dot2f(get2<0>(w7[r]), get2<0>(hv), acc[r]);
        acc[r] = dot2f(get2<1>(w7[r]), get2<1>(hv), acc[r]);
        acc[r] = dot2f(get2<2>(w7[r]), get2<2>(hv), acc[r]);
        acc[r] = dot2f(get2<3>(w7[r]), get2<3>(hv), acc[r]);
      }
    }

    // broadcast xp gate-pairs across the quad (lane kq holds gate kq)
    const int xi = (int)xq0;
    const unsigned xg0 = (unsigned)__builtin_amdgcn_mov_dpp(xi, 0x00, 0xF, 0xF, true);
    const unsigned xg1 = (unsigned)__builtin_amdgcn_mov_dpp(xi, 0x55, 0xF, 0xF, true);
    const unsigned xg2 = (unsigned)__builtin_amdgcn_mov_dpp(xi, 0xAA, 0xF, 0xF, true);
    const unsigned xg3 = (unsigned)__builtin_amdgcn_mov_dpp(xi, 0xFF, 0xF, 0xF, true);

    // quad reduction (commutative adds -> bitwise identical in all 4 lanes)
    float pre[8];
    #pragma unroll
    for (int r = 0; r < 8; ++r) {
      float s = acc[r];
      s = dppadd<0xB1>(s);
      s = dppadd<0x4E>(s);
      pre[r] = s;
    }
    pre[0] += xhalf(xg0, 0); pre[4] += xhalf(xg0, 1);
    pre[1] += xhalf(xg1, 0); pre[5] += xhalf(xg1, 1);
    pre[2] += xhalf(xg2, 0); pre[6] += xhalf(xg2, 1);
    pre[3] += xhalf(xg3, 0); pre[7] += xhalf(xg3, 1);

    // activations (i,f,g,o) for units j0, j0+1 (all 4 lanes, identical)
    c0 = sigmf_(pre[1]) * c0 + sigmf_(pre[0]) * tanhf_(pre[2]);
    const float h0 = sigmf_(pre[3]) * tanhf_(c0);
    c1 = sigmf_(pre[5]) * c1 + sigmf_(pre[4]) * tanhf_(pre[6]);
    const float h1 = sigmf_(pre[7]) * tanhf_(c1);

    if (kq == 0) {
      h2 hh = {(_Float16)h0, (_Float16)h1};
      *(h2*)(hbuf + ((size_t)wb * 4 + (j0 >> 6)) * HQ + (j0 & 63)) = hh;
    }

    // logit-diff wave partial (nonzero only on kq==0 lanes)
    float p = (kq == 0) ? (h0 * dw0 + h1 * dw1) : 0.0f;
    p = dppadd<0xB1>(p);   // quad
    p = dppadd<0x4E>(p);
    p = dppadd<0x124>(p);  // row-of-16
    p = dppadd<0x128>(p);
    p = dppadd<0x142>(p);  // rows -> lane 63
    p = dppadd<0x143>(p);
    if (lane == 63) pbuf[rb * 8 + (tid >> 6)] = p;

    __syncthreads();   // h_t and wave partials visible

    float pv = pbuf[rb * 8 + (lane & 7)];
    pv = dppadd<0xB1>(pv);
    pv = dppadd<0x4E>(pv);
    pv = dppadd<0x12C>(pv);
    const float d = pv + db;
    const float gf = (d > 0.0f) ? 1.0f : 0.0f;   // argmax (ties -> class 0)

    if (kq == 0) {
      const float wv0 = gf * h0, wv1 = gf * h1;
      inc0 += wv0; inc1 += wv1;
      float2 ov;
      ov.x = 2.0f * h0 - wv0 * fw0 + inc0 * dfw0;
      ov.y = 2.0f * h1 - wv1 * fw1 + inc1 * dfw1;
      *(float2*)(outb + (size_t)t * HID + j0) = ov;
    }

    xq0 = xq1; xq1 = xq2;
  }

  if (kq == 0) {
    float2 tv; tv.x = inc0; tv.y = inc1;
    *(float2*)(tot + b * HID + j0) = tv;
  }
}

// ---------------------------------------------------------------------------
// K3: out += tot[b,j] * bw[j]   (suffix total term), vectorized float4
// ---------------------------------------------------------------------------
__global__ __launch_bounds__(256) void k3_add(
    float* __restrict__ out, const float* __restrict__ tot,
    const float* __restrict__ bw) {
  const int gid = blockIdx.x * 256 + threadIdx.x;
  const size_t e = (size_t)gid * 4;
  const int b  = (int)(e >> 20);             // 4096*256 = 2^20 elems per batch
  const int jb = ((int)(e & 255)) >> 2;
  float4 v = ((float4*)out)[gid];
  const float4 tt = ((const float4*)tot)[b * 64 + jb];
  const float4 bb = ((const float4*)bw)[jb];
  v.x += tt.x * bb.x; v.y += tt.y * bb.y;
  v.z += tt.z * bb.z; v.w += tt.w * bb.w;
  ((float4*)out)[gid] = v;
}

extern "C" void kernel_launch(void* const* d_in, const int* in_sizes, int n_in,
                              void* d_out, int out_size, void* d_ws, size_t ws_size,
                              hipStream_t stream) {
  const float* x    = (const float*)d_in[0];
  const float* Wih  = (const float*)d_in[1];
  const float* Whh  = (const float*)d_in[2];
  const float* bih  = (const float*)d_in[3];
  const float* bhh  = (const float*)d_in[4];
  const float* Wlin = (const float*)d_in[5];
  const float* blin = (const float*)d_in[6];
  const float* fw   = (const float*)d_in[7];
  const float* bw   = (const float*)d_in[8];
  float* out = (float*)d_out;

  // Workspace: xp f16 [65536][1024] = 128 MiB, tot f32 [16][256], wres 64 KiB
  _Float16* xpw  = (_Float16*)d_ws;
  float*    tot  = (float*)((char*)d_ws + (size_t)BATCH * T_SEQ * GATES * 2);
  _Float16* wres = (_Float16*)((char*)d_ws + (size_t)BATCH * T_SEQ * GATES * 2 + 16384);

  k0_pack<<<dim3(1), dim3(512), 0, stream>>>(Whh, wres);

  k1_xproj<<<dim3(4096), dim3(256), 0, stream>>>(x, Wih, bih, bhh, xpw);

  (void)hipFuncSetAttribute((const void*)k2_lstm,
                            hipFuncAttributeMaxDynamicSharedMemorySize, K2_LDS);
  k2_lstm<<<dim3(BATCH), dim3(512), K2_LDS, stream>>>(xpw, Whh, wres, Wlin, blin,
                                                      fw, bw, out, tot);

  k3_add<<<dim3(16384), dim3(256), 0, stream>>>(out, tot, bw);
}

// Round 5
// 9202.022 us; speedup vs baseline: 1.4072x; 1.0177x over previous
//
#include <hip/hip_runtime.h>
#include <cstdint>
#include <cstddef>

// Problem constants (B,T,D,H,L = 16,4096,256,256,2)
#define T_SEQ 4096
#define BATCH 16
#define HID   256
#define GATES 1024   // 4*H, torch gate order i,f,g,o
#define DIN   256

typedef _Float16 h2 __attribute__((ext_vector_type(2)));
typedef _Float16 h8 __attribute__((ext_vector_type(8)));
typedef float    f4 __attribute__((ext_vector_type(4)));

// ---- K2 geometry -----------------------------------------------------------
// 512 threads/WG, one WG per batch. Thread (kq=tid&3, u2=tid>>2) owns the
// 8 gate rows {i,f,g,o} x {j0=2*u2, j1=j0+1} restricted to K in [64*kq,64*kq+64).
// Per-row 32 h2 weights split by h8-chunk:
//   chunks 0..4 -> VGPR (160 VGPRs, pinned by asm-keep so the compiler cannot
//                  rematerialize the loads -- round-4 lesson: launch_bounds is
//                  only a cap, the remat heuristic re-loaded f32 weights from
//                  L2 every step = 640KB/WG/step = the whole 5320cyc step)
//   chunks 5,6  -> LDS [r][tid] (2 x 64KB resident, conflict-free b128)
//   chunk  7    -> L2-packed global wres [r][tid], streamed each step
// h double-buffer padded: [2][4][72] f16 -> quarter bases on banks {0,4,8,12}.
#define HQ 72
#define LDSW_BYTES  (2 * 512 * 128)                 // 131072 (w5 + w6)
#define K2HBUF      (2 * 4 * HQ * 2)                // 1152
#define K2PBUF      (2 * 8 * 4)                     // 64
#define K2_LDS      (LDSW_BYTES + K2HBUF + K2PBUF)  // 132288

__device__ __forceinline__ float dot2f(h2 a, h2 b, float c) {
#if __has_builtin(__builtin_amdgcn_fdot2)
  return __builtin_amdgcn_fdot2(a, b, c, false);
#else
  return c + (float)a[0] * (float)b[0] + (float)a[1] * (float)b[1];
#endif
}

template <int I>
__device__ __forceinline__ h2 get2(h8 v) { return (h2){v[2 * I], v[2 * I + 1]}; }

// DPP add: x + dpp_perm(x).  CTRL: 0xB1=xor1, 0x4E=xor2, 0x124=ror:4,
// 0x128=ror:8, 0x12C=ror:12, 0x142=row_bcast15, 0x143=row_bcast31.
template <int CTRL>
__device__ __forceinline__ float dppadd(float x) {
  int v = __builtin_amdgcn_mov_dpp(__float_as_int(x), CTRL, 0xF, 0xF, true);
  return x + __int_as_float(v);
}

__device__ __forceinline__ float xhalf(unsigned u, int hi) {
  h2 p; __builtin_memcpy(&p, &u, 4);
  return hi ? (float)p[1] : (float)p[0];
}

__device__ __forceinline__ float sigmf_(float x) {
  x = fminf(fmaxf(x, -30.0f), 30.0f);
  return 1.0f / (1.0f + __expf(-x));
}
__device__ __forceinline__ float tanhf_(float x) {
  x = fminf(fmaxf(x, -15.0f), 15.0f);
  const float e = __expf(2.0f * x);
  return (e - 1.0f) / (e + 1.0f);
}

__device__ __forceinline__ h8 cvt8(float4 a, float4 b) {
  return (h8){(_Float16)a.x, (_Float16)a.y, (_Float16)a.z, (_Float16)a.w,
              (_Float16)b.x, (_Float16)b.y, (_Float16)b.z, (_Float16)b.w};
}

// ---------------------------------------------------------------------------
// K0: pack chunk-7 weight slices (h indices [kk+56,kk+64)) as f16 in the
// exact per-thread layout K2 streams each step: wres[r*512+tid] = h8.
// ---------------------------------------------------------------------------
__global__ __launch_bounds__(512) void k0_pack(const float* __restrict__ Whh,
                                               _Float16* __restrict__ wres) {
  const int tid = threadIdx.x;
  const int kq = tid & 3, u2 = tid >> 2;
  const int j0 = 2 * u2, kk = kq * 64;
  #pragma unroll
  for (int r = 0; r < 8; ++r) {
    const int row = (r & 3) * 256 + j0 + (r >> 2);
    const float* wp = Whh + (size_t)row * HID + kk + 56;
    const float4 f0 = *(const float4*)wp;
    const float4 f1 = *(const float4*)(wp + 4);
    *(h8*)(wres + ((size_t)r * 512 + tid) * 8) = cvt8(f0, f1);
  }
}

// ---------------------------------------------------------------------------
// K1: xp[m][g] = sum_k x[m][k]*Wih[g][k] + bih[g] + bhh[g], stored f16.
// 256x64 supertile per 256-thread WG.  MFMA f32_16x16x32_f16.
// ---------------------------------------------------------------------------
__global__ __launch_bounds__(256) void k1_xproj(
    const float* __restrict__ x, const float* __restrict__ Wih,
    const float* __restrict__ bih, const float* __restrict__ bhh,
    _Float16* __restrict__ xp) {
  const int bid = blockIdx.x;
  const int ms = bid >> 4;          // 256 M-supertiles of 256 rows
  const int nt = bid & 15;          // 16 N-tiles of 64 cols
  const int tid = threadIdx.x;
  const int wv = tid >> 6;
  const int l  = tid & 63;
  const int lr = l & 15;
  const int lq = l >> 4;

  f4 acc[4][4] = {};
  for (int ks = 0; ks < 8; ++ks) {
    const int k0 = ks * 32 + lq * 8;
    h8 bf[4];
    #pragma unroll
    for (int n = 0; n < 4; ++n) {
      const int col = nt * 64 + n * 16 + lr;
      const float* wr = Wih + (size_t)col * DIN + k0;
      bf[n] = cvt8(*(const float4*)wr, *(const float4*)(wr + 4));
    }
    #pragma unroll
    for (int m = 0; m < 4; ++m) {
      const int arow = ms * 256 + m * 64 + wv * 16 + lr;
      const float* xr = x + (size_t)arow * DIN + k0;
      const h8 af = cvt8(*(const float4*)xr, *(const float4*)(xr + 4));
      #pragma unroll
      for (int n = 0; n < 4; ++n)
        acc[m][n] = __builtin_amdgcn_mfma_f32_16x16x32_f16(af, bf[n], acc[m][n], 0, 0, 0);
    }
  }
  #pragma unroll
  for (int n = 0; n < 4; ++n) {
    const int col = nt * 64 + n * 16 + lr;
    const float bias = bih[col] + bhh[col];
    #pragma unroll
    for (int m = 0; m < 4; ++m) {
      #pragma unroll
      for (int rI = 0; rI < 4; ++rI) {
        const int row = ms * 256 + m * 64 + wv * 16 + lq * 4 + rI;
        xp[(size_t)row * GATES + col] = (_Float16)(acc[m][n][rI] + bias);
      }
    }
  }
}

// ---------------------------------------------------------------------------
// K2: sequential LSTM, one WG per batch.  R=8/S=4 decomposition, DPP quad
// reduction, single barrier per step, fused epilogue part A:
//   out = 2h - w*fw + inc*(fw-bw);  tot saved for K3.
// LDS 132KB forces 1 WG/CU = 2 waves/EU; pin that so the VGPR budget is wide.
// ---------------------------------------------------------------------------
__global__
__attribute__((amdgpu_flat_work_group_size(512, 512), amdgpu_waves_per_eu(2)))
void k2_lstm(
    const _Float16* __restrict__ xp, const float* __restrict__ Whh,
    const _Float16* __restrict__ wres,
    const float* __restrict__ Wlin, const float* __restrict__ blin,
    const float* __restrict__ fw, const float* __restrict__ bw,
    float* __restrict__ out, float* __restrict__ tot) {
  extern __shared__ __align__(16) char smem[];
  _Float16* w5   = (_Float16*)smem;                         // [8][512][8] f16
  _Float16* w6   = (_Float16*)(smem + 65536);               // [8][512][8] f16
  _Float16* hbuf = (_Float16*)(smem + LDSW_BYTES);          // [2][4][72] f16
  float*    pbuf = (float*)(smem + LDSW_BYTES + K2HBUF);    // [2][8] f32

  const int b    = blockIdx.x;
  const int tid  = threadIdx.x;
  const int lane = tid & 63;
  const int kq   = tid & 3;
  const int u2   = tid >> 2;
  const int j0   = 2 * u2;
  const int kk   = kq * 64;

  if (tid < 144) ((float*)hbuf)[tid] = 0.0f;   // zero h-buffer 0 (incl. pad)

  // Register-resident weights: chunks 0..4 of each of the 8 rows.
  h8 wreg[8][5];
  #pragma unroll
  for (int r = 0; r < 8; ++r) {
    const int row = (r & 3) * 256 + j0 + (r >> 2);
    const float* wp = Whh + (size_t)row * HID + kk;
    #pragma unroll
    for (int c = 0; c < 5; ++c)
      wreg[r][c] = cvt8(*(const float4*)(wp + c * 8), *(const float4*)(wp + c * 8 + 4));
    // chunks 5,6 -> LDS, layout [r][tid]
    *(h8*)(w5 + ((size_t)r * 512 + tid) * 8) =
        cvt8(*(const float4*)(wp + 40), *(const float4*)(wp + 44));
    *(h8*)(w6 + ((size_t)r * 512 + tid) * 8) =
        cvt8(*(const float4*)(wp + 48), *(const float4*)(wp + 52));
  }
  // Pin the 40 h8 weight values into VGPRs: opaque to the optimizer, so the
  // remat heuristic cannot re-load them from global inside the t-loop.
  #pragma unroll
  for (int r = 0; r < 8; ++r)
    #pragma unroll
    for (int c = 0; c < 5; ++c)
      asm volatile("" : "+v"(wreg[r][c]));

  const float fw0 = fw[j0], fw1 = fw[j0 + 1];
  const float dfw0 = fw0 - bw[j0], dfw1 = fw1 - bw[j0 + 1];
  const float dw0 = Wlin[HID + j0] - Wlin[j0];
  const float dw1 = Wlin[HID + j0 + 1] - Wlin[j0 + 1];
  const float db  = blin[1] - blin[0];

  float c0 = 0.f, c1 = 0.f, inc0 = 0.f, inc1 = 0.f;

  const unsigned* xpu = (const unsigned*)(xp + (size_t)b * T_SEQ * GATES);
  const int xoff = kq * 128 + u2;           // dword index within a step
  float* outb = out + (size_t)b * T_SEQ * HID;
  const h8* wres8 = (const h8*)wres;

  unsigned xq0 = xpu[xoff];
  unsigned xq1 = xpu[512 + xoff];

  __syncthreads();

  #pragma unroll 1
  for (int t = 0; t < T_SEQ; ++t) {
    const int rb = t & 1, wb = rb ^ 1;

    int tp = t + 2; if (tp > T_SEQ - 1) tp = T_SEQ - 1;
    const unsigned xq2 = xpu[(size_t)tp * 512 + xoff];

    // issue chunk-7 weight stream early (L2-resident, coalesced)
    h8 w7[8];
    #pragma unroll
    for (int r = 0; r < 8; ++r) w7[r] = wres8[r * 512 + tid];

    float acc[8] = {0.f, 0.f, 0.f, 0.f, 0.f, 0.f, 0.f, 0.f};
    const _Float16* hb = hbuf + ((size_t)rb * 4 + kq) * HQ;

    #pragma unroll
    for (int c = 0; c < 5; ++c) {
      const h8 hv = *(const h8*)(hb + c * 8);
      #pragma unroll
      for (int r = 0; r < 8; ++r) {
        acc[r] = dot2f(get2<0>(wreg[r][c]), get2<0>(hv), acc[r]);
        acc[r] = dot2f(get2<1>(wreg[r][c]), get2<1>(hv), acc[r]);
        acc[r] = dot2f(get2<2>(wreg[r][c]), get2<2>(hv), acc[r]);
        acc[r] = dot2f(get2<3>(wreg[r][c]), get2<3>(hv), acc[r]);
      }
    }
    {  // chunk 5 from LDS
      const h8 hv = *(const h8*)(hb + 40);
      #pragma unroll
      for (int r = 0; r < 8; ++r) {
        const h8 wv = *(const h8*)(w5 + ((size_t)r * 512 + tid) * 8);
        acc[r] = dot2f(get2<0>(wv), get2<0>(hv), acc[r]);
        acc[r] = dot2f(get2<1>(wv), get2<1>(hv), acc[r]);
        acc[r] = dot2f(get2<2>(wv), get2<2>(hv), acc[r]);
        acc[r] = dot2f(get2<3>(wv), get2<3>(hv), acc[r]);
      }
    }
    {  // chunk 6 from LDS
      const h8 hv = *(const h8*)(hb + 48);
      #pragma unroll
      for (int r = 0; r < 8; ++r) {
        const h8 wv = *(const h8*)(w6 + ((size_t)r * 512 + tid) * 8);
        acc[r] = dot2f(get2<0>(wv), get2<0>(hv), acc[r]);
        acc[r] = dot2f(get2<1>(wv), get2<1>(hv), acc[r]);
        acc[r] = dot2f(get2<2>(wv), get2<2>(hv), acc[r]);
        acc[r] = dot2f(get2<3>(wv), get2<3>(hv), acc[r]);
      }
    }
    {  // chunk 7 from global (already in w7)
      const h8 hv = *(const h8*)(hb + 56);
      #pragma unroll
      for (int r = 0; r < 8; ++r) {
        acc[r] = dot2f(get2<0>(w7[r]), get2<0>(hv), acc[r]);
        acc[r] = dot2f(get2<1>(w7[r]), get2<1>(hv), acc[r]);
        acc[r] = dot2f(get2<2>(w7[r]), get2<2>(hv), acc[r]);
        acc[r] = dot2f(get2<3>(w7[r]), get2<3>(hv), acc[r]);
      }
    }

    // broadcast xp gate-pairs across the quad (lane kq holds gate kq)
    const int xi = (int)xq0;
    const unsigned xg0 = (unsigned)__builtin_amdgcn_mov_dpp(xi, 0x00, 0xF, 0xF, true);
    const unsigned xg1 = (unsigned)__builtin_amdgcn_mov_dpp(xi, 0x55, 0xF, 0xF, true);
    const unsigned xg2 = (unsigned)__builtin_amdgcn_mov_dpp(xi, 0xAA, 0xF, 0xF, true);
    const unsigned xg3 = (unsigned)__builtin_amdgcn_mov_dpp(xi, 0xFF, 0xF, 0xF, true);

    // quad reduction (commutative adds -> bitwise identical in all 4 lanes)
    float pre[8];
    #pragma unroll
    for (int r = 0; r < 8; ++r) {
      float s = acc[r];
      s = dppadd<0xB1>(s);
      s = dppadd<0x4E>(s);
      pre[r] = s;
    }
    pre[0] += xhalf(xg0, 0); pre[4] += xhalf(xg0, 1);
    pre[1] += xhalf(xg1, 0); pre[5] += xhalf(xg1, 1);
    pre[2] += xhalf(xg2, 0); pre[6] += xhalf(xg2, 1);
    pre[3] += xhalf(xg3, 0); pre[7] += xhalf(xg3, 1);

    // activations (i,f,g,o) for units j0, j0+1 (all 4 lanes, identical)
    c0 = sigmf_(pre[1]) * c0 + sigmf_(pre[0]) * tanhf_(pre[2]);
    const float h0 = sigmf_(pre[3]) * tanhf_(c0);
    c1 = sigmf_(pre[5]) * c1 + sigmf_(pre[4]) * tanhf_(pre[6]);
    const float h1 = sigmf_(pre[7]) * tanhf_(c1);

    if (kq == 0) {
      h2 hh = {(_Float16)h0, (_Float16)h1};
      *(h2*)(hbuf + ((size_t)wb * 4 + (j0 >> 6)) * HQ + (j0 & 63)) = hh;
    }

    // logit-diff wave partial (nonzero only on kq==0 lanes)
    float p = (kq == 0) ? (h0 * dw0 + h1 * dw1) : 0.0f;
    p = dppadd<0xB1>(p);   // quad
    p = dppadd<0x4E>(p);
    p = dppadd<0x124>(p);  // row-of-16
    p = dppadd<0x128>(p);
    p = dppadd<0x142>(p);  // rows -> lane 63
    p = dppadd<0x143>(p);
    if (lane == 63) pbuf[rb * 8 + (tid >> 6)] = p;

    __syncthreads();   // h_t and wave partials visible

    float pv = pbuf[rb * 8 + (lane & 7)];
    pv = dppadd<0xB1>(pv);
    pv = dppadd<0x4E>(pv);
    pv = dppadd<0x12C>(pv);
    const float d = pv + db;
    const float gf = (d > 0.0f) ? 1.0f : 0.0f;   // argmax (ties -> class 0)

    if (kq == 0) {
      const float wv0 = gf * h0, wv1 = gf * h1;
      inc0 += wv0; inc1 += wv1;
      float2 ov;
      ov.x = 2.0f * h0 - wv0 * fw0 + inc0 * dfw0;
      ov.y = 2.0f * h1 - wv1 * fw1 + inc1 * dfw1;
      *(float2*)(outb + (size_t)t * HID + j0) = ov;
    }

    xq0 = xq1; xq1 = xq2;
  }

  if (kq == 0) {
    float2 tv; tv.x = inc0; tv.y = inc1;
    *(float2*)(tot + b * HID + j0) = tv;
  }
}

// ---------------------------------------------------------------------------
// K3: out += tot[b,j] * bw[j]   (suffix total term), vectorized float4
// ---------------------------------------------------------------------------
__global__ __launch_bounds__(256) void k3_add(
    float* __restrict__ out, const float* __restrict__ tot,
    const float* __restrict__ bw) {
  const int gid = blockIdx.x * 256 + threadIdx.x;
  const size_t e = (size_t)gid * 4;
  const int b  = (int)(e >> 20);             // 4096*256 = 2^20 elems per batch
  const int jb = ((int)(e & 255)) >> 2;
  float4 v = ((float4*)out)[gid];
  const float4 tt = ((const float4*)tot)[b * 64 + jb];
  const float4 bb = ((const float4*)bw)[jb];
  v.x += tt.x * bb.x; v.y += tt.y * bb.y;
  v.z += tt.z * bb.z; v.w += tt.w * bb.w;
  ((float4*)out)[gid] = v;
}

extern "C" void kernel_launch(void* const* d_in, const int* in_sizes, int n_in,
                              void* d_out, int out_size, void* d_ws, size_t ws_size,
                              hipStream_t stream) {
  const float* x    = (const float*)d_in[0];
  const float* Wih  = (const float*)d_in[1];
  const float* Whh  = (const float*)d_in[2];
  const float* bih  = (const float*)d_in[3];
  const float* bhh  = (const float*)d_in[4];
  const float* Wlin = (const float*)d_in[5];
  const float* blin = (const float*)d_in[6];
  const float* fw   = (const float*)d_in[7];
  const float* bw   = (const float*)d_in[8];
  float* out = (float*)d_out;

  // Workspace: xp f16 [65536][1024] = 128 MiB, tot f32 [16][256], wres 64 KiB
  _Float16* xpw  = (_Float16*)d_ws;
  float*    tot  = (float*)((char*)d_ws + (size_t)BATCH * T_SEQ * GATES * 2);
  _Float16* wres = (_Float16*)((char*)d_ws + (size_t)BATCH * T_SEQ * GATES * 2 + 16384);

  k0_pack<<<dim3(1), dim3(512), 0, stream>>>(Whh, wres);

  k1_xproj<<<dim3(4096), dim3(256), 0, stream>>>(x, Wih, bih, bhh, xpw);

  (void)hipFuncSetAttribute((const void*)k2_lstm,
                            hipFuncAttributeMaxDynamicSharedMemorySize, K2_LDS);
  k2_lstm<<<dim3(BATCH), dim3(512), K2_LDS, stream>>>(xpw, Whh, wres, Wlin, blin,
                                                      fw, bw, out, tot);

  k3_add<<<dim3(16384), dim3(256), 0, stream>>>(out, tot, bw);
}